// Round 4
// baseline (1343.102 us; speedup 1.0000x reference)
//
#include <hip/hip_runtime.h>
#include <stdint.h>

#define N_POINTS   1048576
#define N_LEVELS   16
#define HASHMAP    524288u        // 1<<19
#define HASH_MASK  (HASHMAP - 1u)
#define PI1        2654435761u
#define PI2        805459861u

typedef float v2  __attribute__((ext_vector_type(2)));   // one table entry (8B)
typedef float v4f __attribute__((ext_vector_type(4)));   // 16B chunk

// int(16 * (32^(1/15))^i) for i in 0..15, replicated exactly from the reference
__constant__ float c_res[16] = {16.f,20.f,25.f,32.f,40.f,50.f,64.f,80.f,
                                101.f,128.f,161.f,203.f,256.f,322.f,406.f,512.f};
// phase order: alternate coarse/fine so adjacent-in-time levels' tables fit L2
__constant__ int c_perm[16] = {0,15,1,14,2,13,3,12,4,11,5,10,6,9,7,8};

// Gather core. TA/TD model (fits rounds 0/1/3): wave gather = ~64 TA cyc
// (1 lane/cyc; dwordx4 = 2 -> round-1 regression) + ~50 cyc L1 line-fill.
// Random 8B gathers get ~0 L1 reuse (4MB table vs 32KB L1), so mark them
// NONTEMPORAL: no L1 allocation -> no fill cost. nt keeps L2 caching.
__device__ __forceinline__ v2 enc_point_level(float x0, float x1, float x2,
                                              const float* __restrict__ tables,
                                              int level, float res) {
    float sx = x0*res, sy = x1*res, sz = x2*res;
    int ix = (int)sx, iy = (int)sy, iz = (int)sz;   // trunc == floor for x>=0
    float fx = sx - (float)ix, fy = sy - (float)iy, fz = sz - (float)iz;
    uint32_t hx0 = (uint32_t)ix,       hx1 = hx0 + 1u;
    uint32_t hy0 = (uint32_t)iy * PI1, hy1 = hy0 + PI1;
    uint32_t hz0 = (uint32_t)iz * PI2, hz1 = hz0 + PI2;
    const v2* __restrict__ tab = (const v2*)tables + (size_t)level * HASHMAP;
    uint32_t e0 = hy0 ^ hz0, e1 = hy1 ^ hz0, e2 = hy0 ^ hz1, e3 = hy1 ^ hz1;
    uint32_t i0 = (hx0 ^ e0) & HASH_MASK;  // (0,0,0)
    uint32_t i1 = (hx1 ^ e0) & HASH_MASK;  // (1,0,0)
    uint32_t i2 = (hx0 ^ e1) & HASH_MASK;  // (0,1,0)
    uint32_t i3 = (hx1 ^ e1) & HASH_MASK;  // (1,1,0)
    uint32_t i4 = (hx0 ^ e2) & HASH_MASK;  // (0,0,1)
    uint32_t i5 = (hx1 ^ e2) & HASH_MASK;  // (1,0,1)
    uint32_t i6 = (hx0 ^ e3) & HASH_MASK;  // (0,1,1)
    uint32_t i7 = (hx1 ^ e3) & HASH_MASK;  // (1,1,1)
    v2 f0 = __builtin_nontemporal_load(tab + i0);
    v2 f1 = __builtin_nontemporal_load(tab + i1);
    v2 f2 = __builtin_nontemporal_load(tab + i2);
    v2 f3 = __builtin_nontemporal_load(tab + i3);
    v2 f4 = __builtin_nontemporal_load(tab + i4);
    v2 f5 = __builtin_nontemporal_load(tab + i5);
    v2 f6 = __builtin_nontemporal_load(tab + i6);
    v2 f7 = __builtin_nontemporal_load(tab + i7);
    float wx1 = fx, wx0 = 1.f - fx;
    float wy1 = fy, wy0 = 1.f - fy;
    float wz1 = fz, wz0 = 1.f - fz;
    float w00 = wy0*wz0, w10 = wy1*wz0, w01 = wy0*wz1, w11 = wy1*wz1;
    float c0 = wx0*w00, c1 = wx1*w00, c2 = wx0*w10, c3 = wx1*w10;
    float c4 = wx0*w01, c5 = wx1*w01, c6 = wx0*w11, c7 = wx1*w11;
    v2 r;
    r.x = c0*f0.x + c1*f1.x + c2*f2.x + c3*f3.x + c4*f4.x + c5*f5.x + c6*f6.x + c7*f7.x;
    r.y = c0*f0.y + c1*f1.y + c2*f2.y + c3*f3.y + c4*f4.y + c5*f5.y + c6*f6.y + c7*f7.y;
    return r;
}

// Pass 1 (phased): blockIdx level-major -> whole device sweeps one level at a
// time -> that level's 4MB table is per-XCD-L2-resident. NT store: ws is
// write-once, keep it out of the table's L2.
__global__ __launch_bounds__(256) void hash_enc_phase(const float* __restrict__ x,
                                                      const float* __restrict__ tables,
                                                      v2* __restrict__ ws) {
    int level = c_perm[blockIdx.x >> 12];           // 4096 blocks per level
    int p = ((blockIdx.x & 4095) << 8) | threadIdx.x;
    v2 r = enc_point_level(x[3*p], x[3*p+1], x[3*p+2], tables, level, c_res[level]);
    __builtin_nontemporal_store(r, ws + (size_t)level * N_POINTS + p);
}

// Pass 2 v3: (L,N,2) -> (N,32f). Changes vs v2 (which ran 1.4 TB/s):
//  - PLAIN loads of ws (not NT): ws (128MB) fits the 256MB L3; NT loads were
//    forcing a 900-cyc HBM path with zero cache help.
//  - 1024 points per block, 4 iters (grid 1024 = exactly 4 blocks/CU): each
//    block reads 8KB contiguous per level-stream instead of 2KB from 4096
//    concurrent blocks -> far fewer live DRAM streams.
// Swizzle col=(c+((p>>3)&7))&7 on a [256][9] v4f tile: conflict-free b128 on
// both sides (verified, SQ_LDS_BANK_CONFLICT=0 in round 3).
__global__ __launch_bounds__(256) void untranspose3(const v2* __restrict__ ws,
                                                    v4f* __restrict__ out) {
    __shared__ v4f tile[256][9];
    int t = threadIdx.x;
    for (int it = 0; it < 4; ++it) {
        int p0 = (blockIdx.x << 10) | (it << 8);
        v2 r[16];
        #pragma unroll
        for (int l = 0; l < 16; ++l)
            r[l] = ws[(size_t)l * N_POINTS + p0 + t];
        int keyw = (t >> 3) & 7;
        #pragma unroll
        for (int c = 0; c < 8; ++c) {
            v4f v = {r[2*c].x, r[2*c].y, r[2*c+1].x, r[2*c+1].y};
            tile[t][(c + keyw) & 7] = v;                 // ds_write_b128
        }
        __syncthreads();
        #pragma unroll
        for (int k = 0; k < 8; ++k) {
            int j  = (k << 8) | t;                       // v4f index in block chunk
            int pl = j >> 3, c = j & 7;
            int key = (pl >> 3) & 7;
            v4f v = tile[pl][(c + key) & 7];             // ds_read_b128
            __builtin_nontemporal_store(v, out + ((size_t)p0 << 3) + j);
        }
        __syncthreads();                                 // tile reuse
    }
}

// Zero-workspace fallback: fused, correct, slow (L2 thrash).
__global__ __launch_bounds__(256) void hash_enc_fused(const float* __restrict__ x,
                                                      const float* __restrict__ tables,
                                                      v2* __restrict__ out) {
    int tid = blockIdx.x * 256 + threadIdx.x;       // 16M threads
    int level = tid & 15;
    int p = tid >> 4;
    v2 r = enc_point_level(x[3*p], x[3*p+1], x[3*p+2], tables, level, c_res[level]);
    out[tid] = r;
}

extern "C" void kernel_launch(void* const* d_in, const int* in_sizes, int n_in,
                              void* d_out, int out_size, void* d_ws, size_t ws_size,
                              hipStream_t stream) {
    const float* x      = (const float*)d_in[0];
    const float* tables = (const float*)d_in[1];
    size_t need = (size_t)N_LEVELS * N_POINTS * sizeof(v2);   // 128 MB
    if (ws_size >= need) {
        hash_enc_phase<<<dim3(65536), dim3(256), 0, stream>>>(x, tables, (v2*)d_ws);
        untranspose3<<<dim3(1024), dim3(256), 0, stream>>>((const v2*)d_ws, (v4f*)d_out);
    } else {
        hash_enc_fused<<<dim3(65536), dim3(256), 0, stream>>>(x, tables, (v2*)d_out);
    }
}

// Round 5
// 557.400 us; speedup vs baseline: 2.4096x; 2.4096x over previous
//
#include <hip/hip_runtime.h>
#include <stdint.h>

#define N_POINTS   1048576
#define N_LEVELS   16
#define HASHMAP    524288u        // 1<<19
#define HASH_MASK  (HASHMAP - 1u)
#define PI1        2654435761u
#define PI2        805459861u

typedef float v2  __attribute__((ext_vector_type(2)));   // one table entry (8B)
typedef float v4f __attribute__((ext_vector_type(4)));   // 16B chunk
typedef int   v4i __attribute__((ext_vector_type(4)));   // SRSRC

// int(16 * (32^(1/15))^i) for i in 0..15, replicated exactly from the reference
__constant__ float c_res[16] = {16.f,20.f,25.f,32.f,40.f,50.f,64.f,80.f,
                                101.f,128.f,161.f,203.f,256.f,322.f,406.f,512.f};
// phase order: alternate coarse/fine so adjacent-in-time levels' tables fit L2
__constant__ int c_perm[16] = {0,15,1,14,2,13,3,12,4,11,5,10,6,9,7,8};

// Raw buffer load with cache-policy control. aux=1 -> sc0 (the CDNA GLC bit):
// L1-BYPASS but L2-ALLOCATE. This is the surgical version of round-4's failed
// `nt` (which turned out to be L2-no-allocate -> FETCH 355MB->1.8GB, 3x slower).
// Random 8B gathers get ~0 L1 reuse (4MB table vs 32KB L1), so the per-miss
// 64B L1 line fill is pure waste; sc0 skips it while keeping the table
// XCD-L2-resident.
__device__ v2 llvm_amdgcn_raw_buffer_load_v2f32(v4i srsrc, int voffset,
                                                int soffset, int aux)
    __asm("llvm.amdgcn.raw.buffer.load.v2f32");

__device__ __forceinline__ v4i make_srsrc(const void* p, uint32_t bytes) {
    union { struct { uint64_t base; uint32_t nrec; uint32_t flags; } s; v4i v; } u;
    u.s.base  = (uint64_t)p;       // stride=0 (raw)
    u.s.nrec  = bytes;             // bounds: voffset+8 <= bytes
    u.s.flags = 0x00020000u;       // raw untyped dword access
    return u.v;
}

// Gather core, buffer-load(sc0) version. Wave-uniform srsrc required
// (buffer_load takes SGPR rsrc) -> only usable when `level` is wave-uniform.
__device__ __forceinline__ v2 enc_point_level_buf(float x0, float x1, float x2,
                                                  v4i tsr, float res) {
    float sx = x0*res, sy = x1*res, sz = x2*res;
    int ix = (int)sx, iy = (int)sy, iz = (int)sz;   // trunc == floor for x>=0
    float fx = sx - (float)ix, fy = sy - (float)iy, fz = sz - (float)iz;
    uint32_t hx0 = (uint32_t)ix,       hx1 = hx0 + 1u;
    uint32_t hy0 = (uint32_t)iy * PI1, hy1 = hy0 + PI1;
    uint32_t hz0 = (uint32_t)iz * PI2, hz1 = hz0 + PI2;
    uint32_t e0 = hy0 ^ hz0, e1 = hy1 ^ hz0, e2 = hy0 ^ hz1, e3 = hy1 ^ hz1;
    int i0 = (int)(((hx0 ^ e0) & HASH_MASK) << 3);  // byte offsets
    int i1 = (int)(((hx1 ^ e0) & HASH_MASK) << 3);
    int i2 = (int)(((hx0 ^ e1) & HASH_MASK) << 3);
    int i3 = (int)(((hx1 ^ e1) & HASH_MASK) << 3);
    int i4 = (int)(((hx0 ^ e2) & HASH_MASK) << 3);
    int i5 = (int)(((hx1 ^ e2) & HASH_MASK) << 3);
    int i6 = (int)(((hx0 ^ e3) & HASH_MASK) << 3);
    int i7 = (int)(((hx1 ^ e3) & HASH_MASK) << 3);
    v2 f0 = llvm_amdgcn_raw_buffer_load_v2f32(tsr, i0, 0, 1);
    v2 f1 = llvm_amdgcn_raw_buffer_load_v2f32(tsr, i1, 0, 1);
    v2 f2 = llvm_amdgcn_raw_buffer_load_v2f32(tsr, i2, 0, 1);
    v2 f3 = llvm_amdgcn_raw_buffer_load_v2f32(tsr, i3, 0, 1);
    v2 f4 = llvm_amdgcn_raw_buffer_load_v2f32(tsr, i4, 0, 1);
    v2 f5 = llvm_amdgcn_raw_buffer_load_v2f32(tsr, i5, 0, 1);
    v2 f6 = llvm_amdgcn_raw_buffer_load_v2f32(tsr, i6, 0, 1);
    v2 f7 = llvm_amdgcn_raw_buffer_load_v2f32(tsr, i7, 0, 1);
    float wx1 = fx, wx0 = 1.f - fx;
    float wy1 = fy, wy0 = 1.f - fy;
    float wz1 = fz, wz0 = 1.f - fz;
    float w00 = wy0*wz0, w10 = wy1*wz0, w01 = wy0*wz1, w11 = wy1*wz1;
    float c0 = wx0*w00, c1 = wx1*w00, c2 = wx0*w10, c3 = wx1*w10;
    float c4 = wx0*w01, c5 = wx1*w01, c6 = wx0*w11, c7 = wx1*w11;
    v2 r;
    r.x = c0*f0.x + c1*f1.x + c2*f2.x + c3*f3.x + c4*f4.x + c5*f5.x + c6*f6.x + c7*f7.x;
    r.y = c0*f0.y + c1*f1.y + c2*f2.y + c3*f3.y + c4*f4.y + c5*f5.y + c6*f6.y + c7*f7.y;
    return r;
}

// Plain-pointer gather core (round-0 verified): used by the fused fallback,
// where `level` is per-lane divergent so buffer srsrc can't be formed.
__device__ __forceinline__ v2 enc_point_level(float x0, float x1, float x2,
                                              const float* __restrict__ tables,
                                              int level, float res) {
    float sx = x0*res, sy = x1*res, sz = x2*res;
    int ix = (int)sx, iy = (int)sy, iz = (int)sz;
    float fx = sx - (float)ix, fy = sy - (float)iy, fz = sz - (float)iz;
    uint32_t hx0 = (uint32_t)ix,       hx1 = hx0 + 1u;
    uint32_t hy0 = (uint32_t)iy * PI1, hy1 = hy0 + PI1;
    uint32_t hz0 = (uint32_t)iz * PI2, hz1 = hz0 + PI2;
    const v2* __restrict__ tab = (const v2*)tables + (size_t)level * HASHMAP;
    uint32_t e0 = hy0 ^ hz0, e1 = hy1 ^ hz0, e2 = hy0 ^ hz1, e3 = hy1 ^ hz1;
    v2 f0 = tab[(hx0 ^ e0) & HASH_MASK], f1 = tab[(hx1 ^ e0) & HASH_MASK];
    v2 f2 = tab[(hx0 ^ e1) & HASH_MASK], f3 = tab[(hx1 ^ e1) & HASH_MASK];
    v2 f4 = tab[(hx0 ^ e2) & HASH_MASK], f5 = tab[(hx1 ^ e2) & HASH_MASK];
    v2 f6 = tab[(hx0 ^ e3) & HASH_MASK], f7 = tab[(hx1 ^ e3) & HASH_MASK];
    float wx1 = fx, wx0 = 1.f - fx;
    float wy1 = fy, wy0 = 1.f - fy;
    float wz1 = fz, wz0 = 1.f - fz;
    float w00 = wy0*wz0, w10 = wy1*wz0, w01 = wy0*wz1, w11 = wy1*wz1;
    float c0 = wx0*w00, c1 = wx1*w00, c2 = wx0*w10, c3 = wx1*w10;
    float c4 = wx0*w01, c5 = wx1*w01, c6 = wx0*w11, c7 = wx1*w11;
    v2 r;
    r.x = c0*f0.x + c1*f1.x + c2*f2.x + c3*f3.x + c4*f4.x + c5*f5.x + c6*f6.x + c7*f7.x;
    r.y = c0*f0.y + c1*f1.y + c2*f2.y + c3*f3.y + c4*f4.y + c5*f5.y + c6*f6.y + c7*f7.y;
    return r;
}

// Pass 1 (phased): blockIdx level-major -> whole device sweeps one level at a
// time -> that level's 4MB table stays per-XCD-L2-resident. ws layout is
// CHUNK-BLOCKED: ws[(chunk c, level, t)] so pass 2 reads contiguous 32KB per
// block instead of 16 streams at 8MB stride. Phase store is still one fully
// coalesced 2KB NT store per block (NT stores proved exactly-128MB clean).
__global__ __launch_bounds__(256) void hash_enc_phase(const float* __restrict__ x,
                                                      const float* __restrict__ tables,
                                                      v2* __restrict__ ws) {
    int level = c_perm[blockIdx.x >> 12];           // 4096 chunks per level
    int c = blockIdx.x & 4095;
    int p = (c << 8) | threadIdx.x;
    v4i tsr = make_srsrc((const char*)tables + (size_t)level * HASHMAP * 8u,
                         HASHMAP * 8u);
    v2 r = enc_point_level_buf(x[3*p], x[3*p+1], x[3*p+2], tsr, c_res[level]);
    __builtin_nontemporal_store(r, ws + ((size_t)c << 12) + (level << 8) + threadIdx.x);
}

// Pass 2: chunk-blocked (c,l,t) -> (N,32f). One contiguous 32KB read per
// block, LDS b128 swizzle transpose (measured SQ_LDS_BANK_CONFLICT=0),
// coalesced 16B NT stores. Plain loads (ws read-once; NT loads are
// L2-no-allocate on this chip — round-4 lesson).
__global__ __launch_bounds__(256) void untranspose4(const v2* __restrict__ ws,
                                                    v4f* __restrict__ out) {
    __shared__ v4f tile[256][9];
    int t = threadIdx.x;
    int c = blockIdx.x;
    const v2* __restrict__ base = ws + ((size_t)c << 12);
    v2 r[16];
    #pragma unroll
    for (int l = 0; l < 16; ++l)
        r[l] = base[(l << 8) | t];
    int keyw = (t >> 3) & 7;
    #pragma unroll
    for (int cc = 0; cc < 8; ++cc) {
        v4f v = {r[2*cc].x, r[2*cc].y, r[2*cc+1].x, r[2*cc+1].y};
        tile[t][(cc + keyw) & 7] = v;                // ds_write_b128
    }
    __syncthreads();
    #pragma unroll
    for (int k = 0; k < 8; ++k) {
        int j  = (k << 8) | t;                       // v4f index in chunk output
        int pl = j >> 3, cc = j & 7;
        int key = (pl >> 3) & 7;
        v4f v = tile[pl][(cc + key) & 7];            // ds_read_b128
        __builtin_nontemporal_store(v, out + ((size_t)c << 11) + j);
    }
}

// Zero-workspace fallback: fused, correct, slow (L2 thrash).
__global__ __launch_bounds__(256) void hash_enc_fused(const float* __restrict__ x,
                                                      const float* __restrict__ tables,
                                                      v2* __restrict__ out) {
    int tid = blockIdx.x * 256 + threadIdx.x;       // 16M threads
    int level = tid & 15;
    int p = tid >> 4;
    v2 r = enc_point_level(x[3*p], x[3*p+1], x[3*p+2], tables, level, c_res[level]);
    out[tid] = r;
}

extern "C" void kernel_launch(void* const* d_in, const int* in_sizes, int n_in,
                              void* d_out, int out_size, void* d_ws, size_t ws_size,
                              hipStream_t stream) {
    const float* x      = (const float*)d_in[0];
    const float* tables = (const float*)d_in[1];
    size_t need = (size_t)N_LEVELS * N_POINTS * sizeof(v2);   // 128 MB
    if (ws_size >= need) {
        hash_enc_phase<<<dim3(65536), dim3(256), 0, stream>>>(x, tables, (v2*)d_ws);
        untranspose4<<<dim3(4096), dim3(256), 0, stream>>>((const v2*)d_ws, (v4f*)d_out);
    } else {
        hash_enc_fused<<<dim3(65536), dim3(256), 0, stream>>>(x, tables, (v2*)d_out);
    }
}

// Round 6
// 551.434 us; speedup vs baseline: 2.4357x; 1.0108x over previous
//
#include <hip/hip_runtime.h>
#include <stdint.h>

#define N_POINTS   1048576
#define N_LEVELS   16
#define HASHMAP    524288u        // 1<<19
#define HASH_MASK  (HASHMAP - 1u)
#define PI1        2654435761u
#define PI2        805459861u
#define NBUCKET    32768          // 15-bit Morton key of res-32 cell

typedef float v2  __attribute__((ext_vector_type(2)));   // one table entry (8B)
typedef float v4f __attribute__((ext_vector_type(4)));   // 16B chunk

// int(16 * (32^(1/15))^i) for i in 0..15, replicated exactly from the reference
__constant__ float c_res[16] = {16.f,20.f,25.f,32.f,40.f,50.f,64.f,80.f,
                                101.f,128.f,161.f,203.f,256.f,322.f,406.f,512.f};
// phase order: alternate coarse/fine so adjacent-in-time levels' tables fit L2
__constant__ int c_perm[16] = {0,15,1,14,2,13,3,12,4,11,5,10,6,9,7,8};

// ---- gather core (round-0 verified). With Morton-sorted points, lanes of a
// wave share cells at coarse levels -> identical gather addresses -> the TA
// merges them into ~1 request/instr instead of 64. No code change needed:
// dedup is a hardware property of same-address lanes within one instruction.
__device__ __forceinline__ v2 enc_point_level(float x0, float x1, float x2,
                                              const float* __restrict__ tables,
                                              int level, float res) {
    float sx = x0*res, sy = x1*res, sz = x2*res;
    int ix = (int)sx, iy = (int)sy, iz = (int)sz;   // trunc == floor for x>=0
    float fx = sx - (float)ix, fy = sy - (float)iy, fz = sz - (float)iz;
    uint32_t hx0 = (uint32_t)ix,       hx1 = hx0 + 1u;
    uint32_t hy0 = (uint32_t)iy * PI1, hy1 = hy0 + PI1;
    uint32_t hz0 = (uint32_t)iz * PI2, hz1 = hz0 + PI2;
    const v2* __restrict__ tab = (const v2*)tables + (size_t)level * HASHMAP;
    uint32_t e0 = hy0 ^ hz0, e1 = hy1 ^ hz0, e2 = hy0 ^ hz1, e3 = hy1 ^ hz1;
    v2 f0 = tab[(hx0 ^ e0) & HASH_MASK], f1 = tab[(hx1 ^ e0) & HASH_MASK];
    v2 f2 = tab[(hx0 ^ e1) & HASH_MASK], f3 = tab[(hx1 ^ e1) & HASH_MASK];
    v2 f4 = tab[(hx0 ^ e2) & HASH_MASK], f5 = tab[(hx1 ^ e2) & HASH_MASK];
    v2 f6 = tab[(hx0 ^ e3) & HASH_MASK], f7 = tab[(hx1 ^ e3) & HASH_MASK];
    float wx1 = fx, wx0 = 1.f - fx;
    float wy1 = fy, wy0 = 1.f - fy;
    float wz1 = fz, wz0 = 1.f - fz;
    float w00 = wy0*wz0, w10 = wy1*wz0, w01 = wy0*wz1, w11 = wy1*wz1;
    float c0 = wx0*w00, c1 = wx1*w00, c2 = wx0*w10, c3 = wx1*w10;
    float c4 = wx0*w01, c5 = wx1*w01, c6 = wx0*w11, c7 = wx1*w11;
    v2 r;
    r.x = c0*f0.x + c1*f1.x + c2*f2.x + c3*f3.x + c4*f4.x + c5*f5.x + c6*f6.x + c7*f7.x;
    r.y = c0*f0.y + c1*f1.y + c2*f2.y + c3*f3.y + c4*f4.y + c5*f5.y + c6*f6.y + c7*f7.y;
    return r;
}

// Morton key of the res-32 cell (15 bits): locality at all scales.
__device__ __forceinline__ uint32_t part1by2(uint32_t v) {
    v = (v | (v << 16)) & 0x030000FFu;
    v = (v | (v <<  8)) & 0x0300F00Fu;
    v = (v | (v <<  4)) & 0x030C30C3u;
    v = (v | (v <<  2)) & 0x09249249u;
    return v;
}
__device__ __forceinline__ uint32_t morton_key(float x0, float x1, float x2) {
    uint32_t ix = (uint32_t)(int)(x0 * 32.f);   // x<1 -> 0..31
    uint32_t iy = (uint32_t)(int)(x1 * 32.f);
    uint32_t iz = (uint32_t)(int)(x2 * 32.f);
    return part1by2(ix) | (part1by2(iy) << 1) | (part1by2(iz) << 2);
}

// ---- sort pass 0a: histogram of Morton buckets
__global__ __launch_bounds__(256) void k_hist(const float* __restrict__ x,
                                              uint32_t* __restrict__ hist) {
    int p = blockIdx.x * 256 + threadIdx.x;
    uint32_t k = morton_key(x[3*p], x[3*p+1], x[3*p+2]);
    atomicAdd(&hist[k], 1u);
}

// ---- 0b: in-place exclusive prefix scan of 32768 counters, one block.
__global__ __launch_bounds__(256) void k_scan(uint32_t* __restrict__ hist) {
    __shared__ uint32_t s[256];
    int t = threadIdx.x;
    uint32_t base = t * (NBUCKET / 256), sum = 0;
    for (int j = 0; j < NBUCKET / 256; ++j) sum += hist[base + j];
    s[t] = sum;
    __syncthreads();
    for (int off = 1; off < 256; off <<= 1) {
        uint32_t v = (t >= off) ? s[t - off] : 0;
        __syncthreads();
        s[t] += v;
        __syncthreads();
    }
    uint32_t run = s[t] - sum;          // exclusive prefix of this thread's range
    for (int j = 0; j < NBUCKET / 256; ++j) {
        uint32_t v = hist[base + j];
        hist[base + j] = run;
        run += v;
    }
}

// ---- 0c: scatter points into Morton order; remember original index.
__global__ __launch_bounds__(256) void k_scatter(const float* __restrict__ x,
                                                 uint32_t* __restrict__ cursor,
                                                 float* __restrict__ xs,
                                                 uint32_t* __restrict__ orig) {
    int p = blockIdx.x * 256 + threadIdx.x;
    float a = x[3*p], b = x[3*p+1], c = x[3*p+2];
    uint32_t k = morton_key(a, b, c);
    uint32_t pos = atomicAdd(&cursor[k], 1u);
    xs[3*pos]   = a;
    xs[3*pos+1] = b;
    xs[3*pos+2] = c;
    orig[pos] = p;
}

// ---- pass 1 (phased, sorted input): blockIdx level-major -> device sweeps one
// level at a time (table XCD-L2-resident). ws chunk-blocked [c][level][t].
__global__ __launch_bounds__(256) void hash_enc_phase(const float* __restrict__ xs,
                                                      const float* __restrict__ tables,
                                                      v2* __restrict__ ws) {
    int level = c_perm[blockIdx.x >> 12];           // 4096 chunks per level
    int c = blockIdx.x & 4095;
    int p = (c << 8) | threadIdx.x;
    v2 r = enc_point_level(xs[3*p], xs[3*p+1], xs[3*p+2], tables, level, c_res[level]);
    __builtin_nontemporal_store(r, ws + ((size_t)c << 12) + (level << 8) + threadIdx.x);
}

// ---- pass 2: read sorted ws coalesced (16 x 512B/wave), assemble the 128B
// row in registers, write to out[orig[p]] as 8 PLAIN 16B stores. Plain (not
// NT): consecutive same-lane stores to one line merge in L2 -> full-line
// writebacks, no amplification (round-1's NT scatter was the failure mode).
__global__ __launch_bounds__(256) void untranspose5(const v2* __restrict__ ws,
                                                    const uint32_t* __restrict__ orig,
                                                    v4f* __restrict__ out) {
    int t = threadIdx.x;
    int c = blockIdx.x;
    const v2* __restrict__ base = ws + ((size_t)c << 12);
    v2 r[16];
    #pragma unroll
    for (int l = 0; l < 16; ++l)
        r[l] = base[(l << 8) | t];
    uint32_t o = orig[(c << 8) | t];
    v4f* __restrict__ row = out + (size_t)o * 8;
    #pragma unroll
    for (int k = 0; k < 8; ++k) {
        v4f v = {r[2*k].x, r[2*k].y, r[2*k+1].x, r[2*k+1].y};
        row[k] = v;
    }
}

// ---- fallback A (no sort space): round-5 unsorted pair, chunk-blocked ws.
__global__ __launch_bounds__(256) void hash_enc_phase_u(const float* __restrict__ x,
                                                        const float* __restrict__ tables,
                                                        v2* __restrict__ ws) {
    int level = c_perm[blockIdx.x >> 12];
    int c = blockIdx.x & 4095;
    int p = (c << 8) | threadIdx.x;
    v2 r = enc_point_level(x[3*p], x[3*p+1], x[3*p+2], tables, level, c_res[level]);
    __builtin_nontemporal_store(r, ws + ((size_t)c << 12) + (level << 8) + threadIdx.x);
}
__global__ __launch_bounds__(256) void untranspose4(const v2* __restrict__ ws,
                                                    v4f* __restrict__ out) {
    __shared__ v4f tile[256][9];
    int t = threadIdx.x;
    int c = blockIdx.x;
    const v2* __restrict__ base = ws + ((size_t)c << 12);
    v2 r[16];
    #pragma unroll
    for (int l = 0; l < 16; ++l)
        r[l] = base[(l << 8) | t];
    int keyw = (t >> 3) & 7;
    #pragma unroll
    for (int cc = 0; cc < 8; ++cc) {
        v4f v = {r[2*cc].x, r[2*cc].y, r[2*cc+1].x, r[2*cc+1].y};
        tile[t][(cc + keyw) & 7] = v;
    }
    __syncthreads();
    #pragma unroll
    for (int k = 0; k < 8; ++k) {
        int j  = (k << 8) | t;
        int pl = j >> 3, cc = j & 7;
        int key = (pl >> 3) & 7;
        v4f v = tile[pl][(cc + key) & 7];
        __builtin_nontemporal_store(v, out + ((size_t)c << 11) + j);
    }
}

// ---- fallback B (zero workspace): fused, correct, slow.
__global__ __launch_bounds__(256) void hash_enc_fused(const float* __restrict__ x,
                                                      const float* __restrict__ tables,
                                                      v2* __restrict__ out) {
    int tid = blockIdx.x * 256 + threadIdx.x;
    int level = tid & 15;
    int p = tid >> 4;
    v2 r = enc_point_level(x[3*p], x[3*p+1], x[3*p+2], tables, level, c_res[level]);
    out[tid] = r;
}

extern "C" void kernel_launch(void* const* d_in, const int* in_sizes, int n_in,
                              void* d_out, int out_size, void* d_ws, size_t ws_size,
                              hipStream_t stream) {
    const float* x      = (const float*)d_in[0];
    const float* tables = (const float*)d_in[1];
    const size_t WS_BYTES   = (size_t)N_LEVELS * N_POINTS * sizeof(v2);   // 128 MB
    const size_t XS_BYTES   = (size_t)N_POINTS * 3 * sizeof(float);       // 12 MB
    const size_t ORIG_BYTES = (size_t)N_POINTS * sizeof(uint32_t);        // 4 MB
    const size_t HIST_BYTES = (size_t)NBUCKET * sizeof(uint32_t);         // 128 KB
    size_t need_sort = WS_BYTES + XS_BYTES + ORIG_BYTES + HIST_BYTES;

    if (ws_size >= need_sort) {
        char* wsb = (char*)d_ws;
        v2*       ws   = (v2*)wsb;
        float*    xs   = (float*)(wsb + WS_BYTES);
        uint32_t* orig = (uint32_t*)(wsb + WS_BYTES + XS_BYTES);
        uint32_t* hist = (uint32_t*)(wsb + WS_BYTES + XS_BYTES + ORIG_BYTES);
        hipMemsetAsync(hist, 0, HIST_BYTES, stream);
        k_hist   <<<dim3(4096),  dim3(256), 0, stream>>>(x, hist);
        k_scan   <<<dim3(1),     dim3(256), 0, stream>>>(hist);
        k_scatter<<<dim3(4096),  dim3(256), 0, stream>>>(x, hist, xs, orig);
        hash_enc_phase<<<dim3(65536), dim3(256), 0, stream>>>(xs, tables, ws);
        untranspose5<<<dim3(4096), dim3(256), 0, stream>>>(ws, orig, (v4f*)d_out);
    } else if (ws_size >= WS_BYTES) {
        hash_enc_phase_u<<<dim3(65536), dim3(256), 0, stream>>>(x, tables, (v2*)d_ws);
        untranspose4<<<dim3(4096), dim3(256), 0, stream>>>((const v2*)d_ws, (v4f*)d_out);
    } else {
        hash_enc_fused<<<dim3(65536), dim3(256), 0, stream>>>(x, tables, (v2*)d_out);
    }
}

// Round 7
// 545.052 us; speedup vs baseline: 2.4642x; 1.0117x over previous
//
#include <hip/hip_runtime.h>
#include <stdint.h>

#define N_POINTS   1048576
#define N_LEVELS   16
#define HASHMAP    524288u        // 1<<19
#define HASH_MASK  (HASHMAP - 1u)
#define PI1        2654435761u
#define PI2        805459861u
#define NBUCKET    32768          // 15-bit Morton key of res-32 cell
#define NCHUNK     128            // NBUCKET / 256

typedef float v2  __attribute__((ext_vector_type(2)));   // one table entry (8B)
typedef float v4f __attribute__((ext_vector_type(4)));   // 16B chunk

// int(16 * (32^(1/15))^i) for i in 0..15, replicated exactly from the reference
__constant__ float c_res[16] = {16.f,20.f,25.f,32.f,40.f,50.f,64.f,80.f,
                                101.f,128.f,161.f,203.f,256.f,322.f,406.f,512.f};
// phase order: alternate coarse/fine so adjacent-in-time levels' tables fit L2
__constant__ int c_perm[16] = {0,15,1,14,2,13,3,12,4,11,5,10,6,9,7,8};

// ---- gather core (round-0 verified). Morton-sorted points: lanes share cells
// at coarse levels -> TA merges same-address lanes -> phase hit 192us (r6),
// its structural floor (fine levels are sparser than the grid; irreducible).
__device__ __forceinline__ v2 enc_point_level(float x0, float x1, float x2,
                                              const float* __restrict__ tables,
                                              int level, float res) {
    float sx = x0*res, sy = x1*res, sz = x2*res;
    int ix = (int)sx, iy = (int)sy, iz = (int)sz;   // trunc == floor for x>=0
    float fx = sx - (float)ix, fy = sy - (float)iy, fz = sz - (float)iz;
    uint32_t hx0 = (uint32_t)ix,       hx1 = hx0 + 1u;
    uint32_t hy0 = (uint32_t)iy * PI1, hy1 = hy0 + PI1;
    uint32_t hz0 = (uint32_t)iz * PI2, hz1 = hz0 + PI2;
    const v2* __restrict__ tab = (const v2*)tables + (size_t)level * HASHMAP;
    uint32_t e0 = hy0 ^ hz0, e1 = hy1 ^ hz0, e2 = hy0 ^ hz1, e3 = hy1 ^ hz1;
    v2 f0 = tab[(hx0 ^ e0) & HASH_MASK], f1 = tab[(hx1 ^ e0) & HASH_MASK];
    v2 f2 = tab[(hx0 ^ e1) & HASH_MASK], f3 = tab[(hx1 ^ e1) & HASH_MASK];
    v2 f4 = tab[(hx0 ^ e2) & HASH_MASK], f5 = tab[(hx1 ^ e2) & HASH_MASK];
    v2 f6 = tab[(hx0 ^ e3) & HASH_MASK], f7 = tab[(hx1 ^ e3) & HASH_MASK];
    float wx1 = fx, wx0 = 1.f - fx;
    float wy1 = fy, wy0 = 1.f - fy;
    float wz1 = fz, wz0 = 1.f - fz;
    float w00 = wy0*wz0, w10 = wy1*wz0, w01 = wy0*wz1, w11 = wy1*wz1;
    float c0 = wx0*w00, c1 = wx1*w00, c2 = wx0*w10, c3 = wx1*w10;
    float c4 = wx0*w01, c5 = wx1*w01, c6 = wx0*w11, c7 = wx1*w11;
    v2 r;
    r.x = c0*f0.x + c1*f1.x + c2*f2.x + c3*f3.x + c4*f4.x + c5*f5.x + c6*f6.x + c7*f7.x;
    r.y = c0*f0.y + c1*f1.y + c2*f2.y + c3*f3.y + c4*f4.y + c5*f5.y + c6*f6.y + c7*f7.y;
    return r;
}

__device__ __forceinline__ uint32_t part1by2(uint32_t v) {
    v = (v | (v << 16)) & 0x030000FFu;
    v = (v | (v <<  8)) & 0x0300F00Fu;
    v = (v | (v <<  4)) & 0x030C30C3u;
    v = (v | (v <<  2)) & 0x09249249u;
    return v;
}
__device__ __forceinline__ uint32_t morton_key(float x0, float x1, float x2) {
    uint32_t ix = (uint32_t)(int)(x0 * 32.f);   // x in [0,1) -> 0..31
    uint32_t iy = (uint32_t)(int)(x1 * 32.f);
    uint32_t iz = (uint32_t)(int)(x2 * 32.f);
    return part1by2(ix) | (part1by2(iy) << 1) | (part1by2(iz) << 2);
}

// ---- 0a: histogram of Morton buckets
__global__ __launch_bounds__(256) void k_hist(const float* __restrict__ x,
                                              uint32_t* __restrict__ hist) {
    int p = blockIdx.x * 256 + threadIdx.x;
    uint32_t k = morton_key(x[3*p], x[3*p+1], x[3*p+2]);
    atomicAdd(&hist[k], 1u);
}

// ---- 0b: PARALLEL chunk scan (replaces round-6's single-block 32K walk,
// which serialized ~45us on one CU). 128 blocks x 256 buckets: LDS scan,
// hist[b] := in-chunk exclusive prefix, aux[chunk] := chunk total.
__global__ __launch_bounds__(256) void k_scan1(uint32_t* __restrict__ hist,
                                               uint32_t* __restrict__ aux) {
    __shared__ uint32_t s[256];
    int t = threadIdx.x;
    int b = (blockIdx.x << 8) | t;
    uint32_t v0 = hist[b];
    s[t] = v0;
    __syncthreads();
    #pragma unroll
    for (int off = 1; off < 256; off <<= 1) {
        uint32_t v = (t >= off) ? s[t - off] : 0;
        __syncthreads();
        s[t] += v;
        __syncthreads();
    }
    hist[b] = s[t] - v0;                     // in-chunk exclusive prefix
    if (t == 255) aux[blockIdx.x] = s[t];    // chunk total
}

// ---- 0c: scatter. Every block redundantly scans the 128 chunk totals in LDS
// (cheaper than a dispatch), then global pos = chunkpref[key>>8] +
// atomicAdd(&hist[key],1). ONE 16B scattered store per point: xs4 =
// (x,y,z, bitcast(orig)) — round 6 paid four (3 dwords + orig).
__global__ __launch_bounds__(256) void k_scatter(const float* __restrict__ x,
                                                 uint32_t* __restrict__ hist,
                                                 const uint32_t* __restrict__ aux,
                                                 v4f* __restrict__ xs4) {
    __shared__ uint32_t cp[NCHUNK];
    int t = threadIdx.x;
    uint32_t a = 0;
    if (t < NCHUNK) { a = aux[t]; cp[t] = a; }
    __syncthreads();
    #pragma unroll
    for (int off = 1; off < NCHUNK; off <<= 1) {
        uint32_t v = 0;
        if (t < NCHUNK && t >= off) v = cp[t - off];
        __syncthreads();
        if (t < NCHUNK) cp[t] += v;
        __syncthreads();
    }
    if (t < NCHUNK) cp[t] -= a;              // exclusive chunk prefix
    __syncthreads();

    int p = blockIdx.x * 256 + t;
    float x0 = x[3*p], x1 = x[3*p+1], x2 = x[3*p+2];
    uint32_t k = morton_key(x0, x1, x2);
    uint32_t pos = cp[k >> 8] + atomicAdd(&hist[k], 1u);
    v4f v = {x0, x1, x2, __uint_as_float((uint32_t)p)};
    xs4[pos] = v;
}

// ---- pass 1 (phased, sorted input): blockIdx level-major -> device sweeps
// one level at a time (table XCD-L2-resident). ws chunk-blocked [c][level][t].
// x read is one coalesced 16B load (w = orig rides free in the same line).
__global__ __launch_bounds__(256) void hash_enc_phase(const v4f* __restrict__ xs4,
                                                      const float* __restrict__ tables,
                                                      v2* __restrict__ ws) {
    int level = c_perm[blockIdx.x >> 12];           // 4096 chunks per level
    int c = blockIdx.x & 4095;
    int p = (c << 8) | threadIdx.x;
    v4f q = xs4[p];
    v2 r = enc_point_level(q.x, q.y, q.z, tables, level, c_res[level]);
    __builtin_nontemporal_store(r, ws + ((size_t)c << 12) + (level << 8) + threadIdx.x);
}

// ---- pass 2: read sorted ws coalesced, assemble the 128B row in registers,
// write to out[orig] as 8 PLAIN 16B stores (L2 merges same-row stores into
// full-line writebacks; NT scatter was round-1's failure). orig from xs4.w.
__global__ __launch_bounds__(256) void untranspose6(const v2* __restrict__ ws,
                                                    const v4f* __restrict__ xs4,
                                                    v4f* __restrict__ out) {
    int t = threadIdx.x;
    int c = blockIdx.x;
    const v2* __restrict__ base = ws + ((size_t)c << 12);
    v2 r[16];
    #pragma unroll
    for (int l = 0; l < 16; ++l)
        r[l] = base[(l << 8) | t];
    uint32_t o = __float_as_uint(xs4[(c << 8) | t].w);
    v4f* __restrict__ row = out + (size_t)o * 8;
    #pragma unroll
    for (int k = 0; k < 8; ++k) {
        v4f v = {r[2*k].x, r[2*k].y, r[2*k+1].x, r[2*k+1].y};
        row[k] = v;
    }
}

// ---- fallback A (no sort space): unsorted phased pair (round-5, 548us-class)
__global__ __launch_bounds__(256) void hash_enc_phase_u(const float* __restrict__ x,
                                                        const float* __restrict__ tables,
                                                        v2* __restrict__ ws) {
    int level = c_perm[blockIdx.x >> 12];
    int c = blockIdx.x & 4095;
    int p = (c << 8) | threadIdx.x;
    v2 r = enc_point_level(x[3*p], x[3*p+1], x[3*p+2], tables, level, c_res[level]);
    __builtin_nontemporal_store(r, ws + ((size_t)c << 12) + (level << 8) + threadIdx.x);
}
__global__ __launch_bounds__(256) void untranspose4(const v2* __restrict__ ws,
                                                    v4f* __restrict__ out) {
    __shared__ v4f tile[256][9];
    int t = threadIdx.x;
    int c = blockIdx.x;
    const v2* __restrict__ base = ws + ((size_t)c << 12);
    v2 r[16];
    #pragma unroll
    for (int l = 0; l < 16; ++l)
        r[l] = base[(l << 8) | t];
    int keyw = (t >> 3) & 7;
    #pragma unroll
    for (int cc = 0; cc < 8; ++cc) {
        v4f v = {r[2*cc].x, r[2*cc].y, r[2*cc+1].x, r[2*cc+1].y};
        tile[t][(cc + keyw) & 7] = v;
    }
    __syncthreads();
    #pragma unroll
    for (int k = 0; k < 8; ++k) {
        int j  = (k << 8) | t;
        int pl = j >> 3, cc = j & 7;
        int key = (pl >> 3) & 7;
        v4f v = tile[pl][(cc + key) & 7];
        __builtin_nontemporal_store(v, out + ((size_t)c << 11) + j);
    }
}

// ---- fallback B (zero workspace): fused, correct, slow.
__global__ __launch_bounds__(256) void hash_enc_fused(const float* __restrict__ x,
                                                      const float* __restrict__ tables,
                                                      v2* __restrict__ out) {
    int tid = blockIdx.x * 256 + threadIdx.x;
    int level = tid & 15;
    int p = tid >> 4;
    v2 r = enc_point_level(x[3*p], x[3*p+1], x[3*p+2], tables, level, c_res[level]);
    out[tid] = r;
}

extern "C" void kernel_launch(void* const* d_in, const int* in_sizes, int n_in,
                              void* d_out, int out_size, void* d_ws, size_t ws_size,
                              hipStream_t stream) {
    const float* x      = (const float*)d_in[0];
    const float* tables = (const float*)d_in[1];
    const size_t WS_BYTES   = (size_t)N_LEVELS * N_POINTS * sizeof(v2);   // 128 MB
    const size_t XS_BYTES   = (size_t)N_POINTS * sizeof(v4f);             // 16 MB
    const size_t HIST_BYTES = (size_t)NBUCKET * sizeof(uint32_t);         // 128 KB
    const size_t AUX_BYTES  = (size_t)NCHUNK * sizeof(uint32_t);          // 512 B
    size_t need_sort = WS_BYTES + XS_BYTES + HIST_BYTES + AUX_BYTES;

    if (ws_size >= need_sort) {
        char* wsb = (char*)d_ws;
        v2*       ws   = (v2*)wsb;
        v4f*      xs4  = (v4f*)(wsb + WS_BYTES);
        uint32_t* hist = (uint32_t*)(wsb + WS_BYTES + XS_BYTES);
        uint32_t* aux  = (uint32_t*)(wsb + WS_BYTES + XS_BYTES + HIST_BYTES);
        hipMemsetAsync(hist, 0, HIST_BYTES, stream);
        k_hist   <<<dim3(4096),   dim3(256), 0, stream>>>(x, hist);
        k_scan1  <<<dim3(NCHUNK), dim3(256), 0, stream>>>(hist, aux);
        k_scatter<<<dim3(4096),   dim3(256), 0, stream>>>(x, hist, aux, xs4);
        hash_enc_phase<<<dim3(65536), dim3(256), 0, stream>>>(xs4, tables, ws);
        untranspose6<<<dim3(4096), dim3(256), 0, stream>>>(ws, xs4, (v4f*)d_out);
    } else if (ws_size >= WS_BYTES) {
        hash_enc_phase_u<<<dim3(65536), dim3(256), 0, stream>>>(x, tables, (v2*)d_ws);
        untranspose4<<<dim3(4096), dim3(256), 0, stream>>>((const v2*)d_ws, (v4f*)d_out);
    } else {
        hash_enc_fused<<<dim3(65536), dim3(256), 0, stream>>>(x, tables, (v2*)d_out);
    }
}

// Round 8
// 481.522 us; speedup vs baseline: 2.7893x; 1.1319x over previous
//
#include <hip/hip_runtime.h>
#include <stdint.h>

#define N_POINTS   1048576
#define N_LEVELS   16
#define HASHMAP    524288u        // 1<<19
#define HASH_MASK  (HASHMAP - 1u)
#define PI1        2654435761u
#define PI2        805459861u
#define NBUCKET    4096           // 12-bit Morton key (res-16 cell)
#define HBLK       256            // hist/scatter blocks
#define PPB        4096           // points per hist/scatter block

typedef float v2  __attribute__((ext_vector_type(2)));   // one table entry (8B)
typedef float v4f __attribute__((ext_vector_type(4)));   // 16B chunk

// int(16 * (32^(1/15))^i) for i in 0..15, replicated exactly from the reference
__constant__ float c_res[16] = {16.f,20.f,25.f,32.f,40.f,50.f,64.f,80.f,
                                101.f,128.f,161.f,203.f,256.f,322.f,406.f,512.f};
// phase order: alternate coarse/fine so adjacent-in-time levels' tables fit L2
__constant__ int c_perm[16] = {0,15,1,14,2,13,3,12,4,11,5,10,6,9,7,8};

// ---- gather core (round-0 verified; at its L2-request floor with sorted input)
__device__ __forceinline__ v2 enc_point_level(float x0, float x1, float x2,
                                              const float* __restrict__ tables,
                                              int level, float res) {
    float sx = x0*res, sy = x1*res, sz = x2*res;
    int ix = (int)sx, iy = (int)sy, iz = (int)sz;   // trunc == floor for x>=0
    float fx = sx - (float)ix, fy = sy - (float)iy, fz = sz - (float)iz;
    uint32_t hx0 = (uint32_t)ix,       hx1 = hx0 + 1u;
    uint32_t hy0 = (uint32_t)iy * PI1, hy1 = hy0 + PI1;
    uint32_t hz0 = (uint32_t)iz * PI2, hz1 = hz0 + PI2;
    const v2* __restrict__ tab = (const v2*)tables + (size_t)level * HASHMAP;
    uint32_t e0 = hy0 ^ hz0, e1 = hy1 ^ hz0, e2 = hy0 ^ hz1, e3 = hy1 ^ hz1;
    v2 f0 = tab[(hx0 ^ e0) & HASH_MASK], f1 = tab[(hx1 ^ e0) & HASH_MASK];
    v2 f2 = tab[(hx0 ^ e1) & HASH_MASK], f3 = tab[(hx1 ^ e1) & HASH_MASK];
    v2 f4 = tab[(hx0 ^ e2) & HASH_MASK], f5 = tab[(hx1 ^ e2) & HASH_MASK];
    v2 f6 = tab[(hx0 ^ e3) & HASH_MASK], f7 = tab[(hx1 ^ e3) & HASH_MASK];
    float wx1 = fx, wx0 = 1.f - fx;
    float wy1 = fy, wy0 = 1.f - fy;
    float wz1 = fz, wz0 = 1.f - fz;
    float w00 = wy0*wz0, w10 = wy1*wz0, w01 = wy0*wz1, w11 = wy1*wz1;
    float c0 = wx0*w00, c1 = wx1*w00, c2 = wx0*w10, c3 = wx1*w10;
    float c4 = wx0*w01, c5 = wx1*w01, c6 = wx0*w11, c7 = wx1*w11;
    v2 r;
    r.x = c0*f0.x + c1*f1.x + c2*f2.x + c3*f3.x + c4*f4.x + c5*f5.x + c6*f6.x + c7*f7.x;
    r.y = c0*f0.y + c1*f1.y + c2*f2.y + c3*f3.y + c4*f4.y + c5*f5.y + c6*f6.y + c7*f7.y;
    return r;
}

__device__ __forceinline__ uint32_t part1by2(uint32_t v) {
    v = (v | (v << 16)) & 0x030000FFu;
    v = (v | (v <<  8)) & 0x0300F00Fu;
    v = (v | (v <<  4)) & 0x030C30C3u;
    v = (v | (v <<  2)) & 0x09249249u;
    return v;
}
// 12-bit Morton of the res-16 cell. Bucket = one res-16 cell (~256 pts = 4
// waves fully inside): res<=32 dedup unchanged-perfect, res 40-80 coarser.
__device__ __forceinline__ uint32_t morton12(float x0, float x1, float x2) {
    uint32_t ix = (uint32_t)(int)(x0 * 16.f);   // x in [0,1) -> 0..15
    uint32_t iy = (uint32_t)(int)(x1 * 16.f);
    uint32_t iz = (uint32_t)(int)(x2 * 16.f);
    return part1by2(ix) | (part1by2(iy) << 1) | (part1by2(iz) << 2);
}

// ---- 0a: per-block LDS histogram -> coalesced row write. ZERO global atomics.
__global__ __launch_bounds__(256) void k_hist(const float* __restrict__ x,
                                              uint32_t* __restrict__ M) {
    __shared__ uint32_t h[NBUCKET];
    int t = threadIdx.x, blk = blockIdx.x;
    for (int j = t; j < NBUCKET; j += 256) h[j] = 0;
    __syncthreads();
    int base = blk * PPB;
    for (int it = 0; it < PPB / 256; ++it) {
        int p = base + it * 256 + t;
        uint32_t k = morton12(x[3*p], x[3*p+1], x[3*p+2]);
        atomicAdd(&h[k], 1u);                    // LDS atomic
    }
    __syncthreads();
    for (int j = t; j < NBUCKET; j += 256)
        M[blk * NBUCKET + j] = h[j];
}

// ---- 0b: per-bucket exclusive scan across the 256 hist-blocks (+ totals T).
// One block per bucket; strided column loads (cheap, 1M dwords total).
__global__ __launch_bounds__(256) void k_scanA(uint32_t* __restrict__ M,
                                               uint32_t* __restrict__ T) {
    __shared__ uint32_t s[256];
    int t = threadIdx.x, b = blockIdx.x;
    uint32_t v0 = M[(size_t)t * NBUCKET + b];
    s[t] = v0;
    __syncthreads();
    #pragma unroll
    for (int off = 1; off < 256; off <<= 1) {
        uint32_t v = (t >= off) ? s[t - off] : 0;
        __syncthreads();
        s[t] += v;
        __syncthreads();
    }
    M[(size_t)t * NBUCKET + b] = s[t] - v0;      // excl. prefix over hist-blocks
    if (t == 255) T[b] = s[t];                   // bucket total
}

// ---- 0c: scatter. Bucket bases from a redundant LDS scan of T (no extra
// dispatch), ranks from LDS cursors. ZERO global atomics; one coalesced read
// + one 16B scattered store per point. xs4 = (x,y,z,bitcast(orig)).
__global__ __launch_bounds__(256) void k_scatter(const float* __restrict__ x,
                                                 const uint32_t* __restrict__ M,
                                                 const uint32_t* __restrict__ T,
                                                 v4f* __restrict__ xs4) {
    __shared__ uint32_t sbase[NBUCKET];          // 16 KB
    __shared__ uint32_t cur[NBUCKET];            // 16 KB
    __shared__ uint32_t mrow[NBUCKET];           // 16 KB
    __shared__ uint32_t ss[256];
    int t = threadIdx.x, blk = blockIdx.x;
    uint32_t loc[16]; uint32_t sum = 0;
    #pragma unroll
    for (int j = 0; j < 16; ++j) { loc[j] = T[t * 16 + j]; sum += loc[j]; }
    ss[t] = sum;
    for (int j = t; j < NBUCKET; j += 256) {
        cur[j] = 0;
        mrow[j] = M[(size_t)blk * NBUCKET + j];
    }
    __syncthreads();
    #pragma unroll
    for (int off = 1; off < 256; off <<= 1) {
        uint32_t v = (t >= off) ? ss[t - off] : 0;
        __syncthreads();
        ss[t] += v;
        __syncthreads();
    }
    uint32_t run = ss[t] - sum;                  // exclusive prefix of thread range
    #pragma unroll
    for (int j = 0; j < 16; ++j) { sbase[t * 16 + j] = run; run += loc[j]; }
    __syncthreads();
    for (int it = 0; it < PPB / 256; ++it) {
        int p = blk * PPB + it * 256 + t;
        float a = x[3*p], b = x[3*p+1], c = x[3*p+2];
        uint32_t k = morton12(a, b, c);
        uint32_t rank = atomicAdd(&cur[k], 1u);  // LDS atomic
        uint32_t pos = sbase[k] + mrow[k] + rank;
        v4f v = {a, b, c, __uint_as_float((uint32_t)p)};
        xs4[pos] = v;
    }
}

// ---- pass 1 (phased, sorted input): blockIdx level-major -> device sweeps
// one level at a time (table XCD-L2-resident). ws chunk-blocked [c][level][t].
__global__ __launch_bounds__(256) void hash_enc_phase(const v4f* __restrict__ xs4,
                                                      const float* __restrict__ tables,
                                                      v2* __restrict__ ws) {
    int level = c_perm[blockIdx.x >> 12];           // 4096 chunks per level
    int c = blockIdx.x & 4095;
    int p = (c << 8) | threadIdx.x;
    v4f q = xs4[p];
    v2 r = enc_point_level(q.x, q.y, q.z, tables, level, c_res[level]);
    __builtin_nontemporal_store(r, ws + ((size_t)c << 12) + (level << 8) + threadIdx.x);
}

// ---- pass 2: cooperative-row stores. Assemble rows in registers, swizzled
// LDS redistribute, then each 8-lane group stores one 128B row: every store
// instr = 8 rows x 2 FULL 64B lines = 16 distinct lines (vs 64 partial for
// per-lane rows) -> scattered-store requests 8 -> 2 per point, full-line
// writes skip read-for-ownership. Plain stores (NT scatter = round-1 failure).
__global__ __launch_bounds__(256) void untranspose7(const v2* __restrict__ ws,
                                                    const v4f* __restrict__ xs4,
                                                    v4f* __restrict__ out) {
    __shared__ v4f rows[256][8];                 // 32 KB
    __shared__ uint32_t ori[256];
    int t = threadIdx.x, c = blockIdx.x;
    const v2* __restrict__ base = ws + ((size_t)c << 12);
    v2 r[16];
    #pragma unroll
    for (int l = 0; l < 16; ++l)
        r[l] = base[(l << 8) | t];
    ori[t] = __float_as_uint(xs4[(c << 8) | t].w);
    #pragma unroll
    for (int q = 0; q < 8; ++q) {
        v4f v = {r[2*q].x, r[2*q].y, r[2*q+1].x, r[2*q+1].y};
        rows[t][(q + t) & 7] = v;                // swizzled: conflict-floor writes
    }
    __syncthreads();
    #pragma unroll
    for (int k = 0; k < 8; ++k) {
        int rr = (k << 5) | (t >> 3);            // row handled by this 8-lane group
        int q  = t & 7;                          // chunk within row
        v4f v = rows[rr][(q + rr) & 7];
        uint32_t o = ori[rr];
        out[(size_t)o * 8 + q] = v;
    }
}

// ---- fallback A (128MB ws only): unsorted phased pair (548us-class)
__global__ __launch_bounds__(256) void hash_enc_phase_u(const float* __restrict__ x,
                                                        const float* __restrict__ tables,
                                                        v2* __restrict__ ws) {
    int level = c_perm[blockIdx.x >> 12];
    int c = blockIdx.x & 4095;
    int p = (c << 8) | threadIdx.x;
    v2 r = enc_point_level(x[3*p], x[3*p+1], x[3*p+2], tables, level, c_res[level]);
    __builtin_nontemporal_store(r, ws + ((size_t)c << 12) + (level << 8) + threadIdx.x);
}
__global__ __launch_bounds__(256) void untranspose4(const v2* __restrict__ ws,
                                                    v4f* __restrict__ out) {
    __shared__ v4f tile[256][9];
    int t = threadIdx.x, c = blockIdx.x;
    const v2* __restrict__ base = ws + ((size_t)c << 12);
    v2 r[16];
    #pragma unroll
    for (int l = 0; l < 16; ++l)
        r[l] = base[(l << 8) | t];
    int keyw = (t >> 3) & 7;
    #pragma unroll
    for (int cc = 0; cc < 8; ++cc) {
        v4f v = {r[2*cc].x, r[2*cc].y, r[2*cc+1].x, r[2*cc+1].y};
        tile[t][(cc + keyw) & 7] = v;
    }
    __syncthreads();
    #pragma unroll
    for (int k = 0; k < 8; ++k) {
        int j  = (k << 8) | t;
        int pl = j >> 3, cc = j & 7;
        int key = (pl >> 3) & 7;
        v4f v = tile[pl][(cc + key) & 7];
        __builtin_nontemporal_store(v, out + ((size_t)c << 11) + j);
    }
}

// ---- fallback B (zero workspace): fused, correct, slow.
__global__ __launch_bounds__(256) void hash_enc_fused(const float* __restrict__ x,
                                                      const float* __restrict__ tables,
                                                      v2* __restrict__ out) {
    int tid = blockIdx.x * 256 + threadIdx.x;
    int level = tid & 15;
    int p = tid >> 4;
    v2 r = enc_point_level(x[3*p], x[3*p+1], x[3*p+2], tables, level, c_res[level]);
    out[tid] = r;
}

extern "C" void kernel_launch(void* const* d_in, const int* in_sizes, int n_in,
                              void* d_out, int out_size, void* d_ws, size_t ws_size,
                              hipStream_t stream) {
    const float* x      = (const float*)d_in[0];
    const float* tables = (const float*)d_in[1];
    const size_t WS_BYTES  = (size_t)N_LEVELS * N_POINTS * sizeof(v2);    // 128 MB
    const size_t XS_BYTES  = (size_t)N_POINTS * sizeof(v4f);              // 16 MB
    const size_t M_BYTES   = (size_t)HBLK * NBUCKET * sizeof(uint32_t);   // 4 MB
    const size_t T_BYTES   = (size_t)NBUCKET * sizeof(uint32_t);          // 16 KB
    size_t need_sort = WS_BYTES + XS_BYTES + M_BYTES + T_BYTES;

    if (ws_size >= need_sort) {
        char* wsb = (char*)d_ws;
        v2*       ws  = (v2*)wsb;
        v4f*      xs4 = (v4f*)(wsb + WS_BYTES);
        uint32_t* M   = (uint32_t*)(wsb + WS_BYTES + XS_BYTES);
        uint32_t* T   = (uint32_t*)(wsb + WS_BYTES + XS_BYTES + M_BYTES);
        k_hist   <<<dim3(HBLK),    dim3(256), 0, stream>>>(x, M);
        k_scanA  <<<dim3(NBUCKET), dim3(256), 0, stream>>>(M, T);
        k_scatter<<<dim3(HBLK),    dim3(256), 0, stream>>>(x, M, T, xs4);
        hash_enc_phase<<<dim3(65536), dim3(256), 0, stream>>>(xs4, tables, ws);
        untranspose7<<<dim3(4096), dim3(256), 0, stream>>>(ws, xs4, (v4f*)d_out);
    } else if (ws_size >= WS_BYTES) {
        hash_enc_phase_u<<<dim3(65536), dim3(256), 0, stream>>>(x, tables, (v2*)d_ws);
        untranspose4<<<dim3(4096), dim3(256), 0, stream>>>((const v2*)d_ws, (v4f*)d_out);
    } else {
        hash_enc_fused<<<dim3(65536), dim3(256), 0, stream>>>(x, tables, (v2*)d_out);
    }
}